// Round 3
// baseline (244.611 us; speedup 1.0000x reference)
//
#include <hip/hip_runtime.h>
#include <stdint.h>

using f32x4  = __attribute__((ext_vector_type(4))) float;
using short8 = __attribute__((ext_vector_type(8))) short;

#define DEVI static __device__ __forceinline__

// float -> bf16 round-to-nearest-even
DEVI unsigned short f2bf(float f) {
  unsigned u = __float_as_uint(f);
  u += 0x7FFFu + ((u >> 16) & 1u);
  return (unsigned short)(u >> 16);
}

// async global->LDS, 16B per lane. LDS dest is wave-uniform base; HW writes
// base + lane*16. Global src is per-lane.
DEVI void gld16(const void* g, void* l) {
  __builtin_amdgcn_global_load_lds(
      reinterpret_cast<const __attribute__((address_space(1))) unsigned int*>(
          reinterpret_cast<uintptr_t>(g)),
      reinterpret_cast<__attribute__((address_space(3))) unsigned int*>(
          reinterpret_cast<uintptr_t>(l)),
      16, 0, 0);
}

// ---------------- K0: zero bn stats + global zero page ----------------
__global__ void k_zero(float* __restrict__ bn, float* __restrict__ zp) {
  const int t = threadIdx.x;
  for (int i = t; i < 768; i += 256) bn[i] = 0.0f;
  for (int i = t; i < 1024; i += 256) zp[i] = 0.0f;
}

// ---------------- K1: per-(b,c) sum / sumsq of x ----------------
__global__ __launch_bounds__(256) void k_stats(const float* __restrict__ x,
                                               float* __restrict__ sums,
                                               float* __restrict__ sumsq) {
  const int bc = blockIdx.x;  // 0..12287
  const float4 v =
      reinterpret_cast<const float4*>(x + (size_t)bc * 1024)[threadIdx.x];
  float s = v.x + v.y + v.z + v.w;
  float q = v.x * v.x + v.y * v.y + v.z * v.z + v.w * v.w;
#pragma unroll
  for (int off = 1; off < 64; off <<= 1) {
    s += __shfl_xor(s, off, 64);
    q += __shfl_xor(q, off, 64);
  }
  __shared__ float ls[4], lq[4];
  const int wv = threadIdx.x >> 6;
  if ((threadIdx.x & 63) == 0) { ls[wv] = s; lq[wv] = q; }
  __syncthreads();
  if (threadIdx.x == 0) {
    sums[bc]  = ls[0] + ls[1] + ls[2] + ls[3];
    sumsq[bc] = lq[0] + lq[1] + lq[2] + lq[3];
  }
}

// ---------------- K2: fold both CSA blocks into fea2 = A*x + B ----------------
__global__ __launch_bounds__(384) void k_coef(
    const float* __restrict__ pmp, const float* __restrict__ psp,
    const float* __restrict__ pmn, const float* __restrict__ psn,
    const float* __restrict__ cw, const int* __restrict__ label,
    const float* __restrict__ sums, const float* __restrict__ sumsq,
    float* __restrict__ Ac, float* __restrict__ Bc) {
  const int b = blockIdx.x;    // 0..31
  const int c = threadIdx.x;   // 0..383
  __shared__ float w0[64], w1[64];
  if (threadIdx.x < 64) w0[threadIdx.x] = cw[b * 64 + threadIdx.x];
  else if (threadIdx.x < 128) w1[threadIdx.x - 64] = cw[2048 + b * 64 + (threadIdx.x - 64)];
  __syncthreads();
  const bool sel = (label[b] == 0);
  const float* m1t = (sel ? pmp : pmn);           // layer 0 tables [K=64][C=384]
  const float* s1t = (sel ? psp : psn);
  const float* m2t = m1t + 64 * 384;              // layer 1
  const float* s2t = s1t + 64 * 384;
  float m1 = 0.f, s1 = 0.f, m2 = 0.f, s2 = 0.f;
  for (int k = 0; k < 64; ++k) {
    const float a0 = w0[k], a1 = w1[k];
    m1 += a0 * m1t[k * 384 + c];
    s1 += a0 * s1t[k * 384 + c];
    m2 += a1 * m2t[k * 384 + c];
    s2 += a1 * s2t[k * 384 + c];
  }
  const int bc = b * 384 + c;
  const float sum = sums[bc], sq = sumsq[bc];
  const float mean = sum * (1.0f / 1024.0f);
  float var = (sq - sum * mean) * (1.0f / 1023.0f);  // ddof=1
  var = fmaxf(var, 0.0f);
  const float sd1 = sqrtf(var + 1e-5f);
  const float a1c = 1.0f + s1 / sd1;
  const float b1c = m1 - mean * (s1 / sd1);
  const float mean1 = a1c * mean + b1c;      // exact mean of affine fea1
  const float var1  = a1c * a1c * var;       // exact ddof=1 var of affine fea1
  const float sd2 = sqrtf(var1 + 1e-5f);
  const float t2 = 1.0f + s2 / sd2;
  Ac[bc] = a1c * t2;
  Bc[bc] = b1c * t2 + m2 - mean1 * (s2 / sd2);
}

// ---------------- K3: fea2 NHWC bf16 = A*x + B (LDS transpose for writes) ----
// grid (128,6): block = 256 pixels x 64 channels
__global__ __launch_bounds__(256) void k_fea(const float* __restrict__ x,
                                             const float* __restrict__ Ac,
                                             const float* __restrict__ Bc,
                                             unsigned short* __restrict__ fea) {
  __shared__ unsigned short tb[256][68];   // +4 pad: bank-conflict-free
  const int t = threadIdx.x;
  const int g0 = blockIdx.x << 8;          // pixel base
  const int b = g0 >> 10;                  // uniform per block
  const int c0 = blockIdx.y * 64;
  const float* xb = x + (((size_t)b * 384) << 10) + (g0 & 1023) + t;
  const float* Ab = Ac + b * 384 + c0;
  const float* Bb = Bc + b * 384 + c0;
#pragma unroll 1
  for (int u8 = 0; u8 < 64; u8 += 8) {
    union { unsigned short us[8]; uint4 v; } pk;
#pragma unroll
    for (int u = 0; u < 8; ++u) {
      const int c = u8 + u;
      pk.us[u] = f2bf(Ab[c] * xb[(size_t)(c0 + c) << 10] + Bb[c]);
    }
    *reinterpret_cast<uint4*>(&tb[t][u8]) = pk.v;
  }
  __syncthreads();
  const int j = t & 7;
#pragma unroll
  for (int rep = 0; rep < 8; ++rep) {
    const int p = rep * 32 + (t >> 3);
    const uint4 v = *reinterpret_cast<const uint4*>(&tb[p][j * 8]);
    *reinterpret_cast<uint4*>(fea + (size_t)(g0 + p) * 384 + c0 + j * 8) = v;
  }
}

// ---------------- K4: conv_w (OIHW f32) -> wb[tap][co][ci] bf16 ----------------
__global__ __launch_bounds__(256) void k_wcvt(const float* __restrict__ w,
                                              unsigned short* __restrict__ wb) {
  const int e = (blockIdx.x * 256 + threadIdx.x) * 4;  // 9*384*384 = 1327104 exact
  const int t = e / (384 * 384);
  const int rem = e - t * (384 * 384);
  const int co = rem / 384;
  const int ci = rem - co * 384;
  union { unsigned short us[4]; uint2 v; } pk;
#pragma unroll
  for (int u = 0; u < 4; ++u)
    pk.us[u] = f2bf(w[(size_t)(co * 384 + ci + u) * 9 + t]);
  *reinterpret_cast<uint2*>(wb + e) = pk.v;
}

// ---------------- K5: implicit-GEMM conv + BN partial stats ----------------
// 256 thr = 4 waves. Block tile: 96co x 256pix (8 rows x 32 cols).
// Wave tile: 96co x 64pix = 6x4 frags of 16x16x32 bf16 MFMA.
// DOUBLE-BUFFERED LDS (2 x 80896 = 161792 B, 1 block/CU):
//   per buffer: [0,55296) W (9 taps x 96co x 32ci, swizzled),
//               [55296,75776) IN (10 rows x 32 cols x 32ci, swizzled),
//               [75776,80896) zero page (replicated per buffer).
// Pipeline (T3/T4): raw s_barrier + counted vmcnt; stage(cc+1) flies under
// compute(cc). vmcnt never drained to 0 until the last chunk.
__global__ __launch_bounds__(256, 1) void k_conv(
    const unsigned short* __restrict__ fea, const unsigned short* __restrict__ wb,
    const unsigned short* __restrict__ zpg, float* __restrict__ out,
    float* __restrict__ bn_sum, float* __restrict__ bn_sq) {
  __shared__ __align__(16) unsigned char lds[161792];
  const int tid = threadIdx.x;
  const int lane = tid & 63, wv = tid >> 6;
  const int pt = blockIdx.x;      // 0..127
  const int ct = blockIdx.y;      // 0..3
  const int b = pt >> 2, h0 = (pt & 3) * 8;
  const int co0 = ct * 96;
  const int wn = wv;              // pixel quarter

  // zero BOTH buffers' zero-pages; drain own LDS writes (raw barriers later)
  for (int i = tid; i < 1280; i += 256) {
    reinterpret_cast<float*>(lds + 75776)[i] = 0.0f;
    reinterpret_cast<float*>(lds + 80896 + 75776)[i] = 0.0f;
  }
  asm volatile("s_waitcnt lgkmcnt(0)" ::: "memory");

  // ---- hoisted LDS read addresses (buffer-relative) ----
  const int l15 = lane & 15, d = lane >> 4;
  const int aoff = l15 * 64 + ((d ^ ((l15 >> 1) & 3)) << 4);
  int baddr[4][3];
#pragma unroll
  for (int n = 0; n < 4; ++n) {
    const int p_out = wn * 64 + n * 16 + l15;
    const int r_out = p_out >> 5, c_out = p_out & 31;
#pragma unroll
    for (int dx = 0; dx < 3; ++dx) {
      const int c = c_out + dx - 1;
      if ((unsigned)c < 32u) {
        const int pix = r_out * 32 + c;
        baddr[n][dx] = 55296 + pix * 64 + ((d ^ ((pix >> 1) & 3)) << 4);
      } else {
        baddr[n][dx] = 75776 + lane * 16;   // zero page (+dy*2048 stays zero)
      }
    }
  }

  // ---- hoisted staging source pointers (advance +64B per ci-chunk) ----
  const unsigned short* wp[14];
#pragma unroll
  for (int j = 0; j < 14; ++j) {
    const int s = wv + 4 * j;
    const int r = s * 16 + (lane >> 2);      // tap*96+co, < 864 when valid
    const int tap = (r * 683) >> 16;         // r/96 exact for r<864
    const int co = r - tap * 96;
    const int dd = (lane & 3) ^ ((co >> 1) & 3);
    wp[j] = wb + ((size_t)(tap * 384 + co0 + co) * 384 + dd * 8);
  }
  const unsigned short* ip[5];
  int istep[5];
#pragma unroll
  for (int j = 0; j < 5; ++j) {
    const int s = wv + 4 * j;
    const int pix = s * 16 + (lane >> 2);    // slab spans one prow
    const int prow = pix >> 5, pcol = pix & 31;
    const int h = h0 - 1 + prow;
    const int dd = (lane & 3) ^ ((pix >> 1) & 3);
    if (h >= 0 && h < 32) {
      ip[j] = fea + ((size_t)((b * 32 + h) * 32 + pcol) * 384 + dd * 8);
      istep[j] = 32;
    } else {
      ip[j] = zpg + lane * 8;
      istep[j] = 0;
    }
  }

  f32x4 acc[6][4] = {};

  // stage a chunk into buffer at byte offset boff, advance source pointers
#define STAGE(boff)                                              \
  do {                                                           \
    _Pragma("unroll")                                            \
    for (int j = 0; j < 14; ++j) {                               \
      if (j < 13 || wv < 2) {                                    \
        gld16(wp[j], lds + (boff) + (wv + 4 * j) * 1024);        \
        wp[j] += 32;                                             \
      }                                                          \
    }                                                            \
    _Pragma("unroll")                                            \
    for (int j = 0; j < 5; ++j) {                                \
      gld16(ip[j], lds + (boff) + 55296 + (wv + 4 * j) * 1024);  \
      ip[j] += istep[j];                                         \
    }                                                            \
  } while (0)

  STAGE(0);

  for (int cc = 0; cc < 12; ++cc) {
    const int coff = (cc & 1) * 80896;
    if (cc) __builtin_amdgcn_s_barrier();    // A: compute(cc-1) reads done
    if (cc < 11) {
      STAGE(((cc + 1) & 1) * 80896);
      // wait for stage(cc); the 19/18 just-issued stay in flight
      if (wv < 2) asm volatile("s_waitcnt vmcnt(19)" ::: "memory");
      else        asm volatile("s_waitcnt vmcnt(18)" ::: "memory");
    } else {
      asm volatile("s_waitcnt vmcnt(0)" ::: "memory");
    }
    __builtin_amdgcn_s_barrier();            // B: buf[cc&1] ready for all
#pragma unroll
    for (int tap = 0; tap < 9; ++tap) {
      const int dy = tap / 3, dx = tap % 3;
      short8 af[6], bf[4];
#pragma unroll
      for (int m = 0; m < 6; ++m)
        af[m] = *reinterpret_cast<const short8*>(lds + coff + aoff + tap * 6144 + m * 1024);
#pragma unroll
      for (int n = 0; n < 4; ++n)
        bf[n] = *reinterpret_cast<const short8*>(lds + coff + baddr[n][dx] + dy * 2048);
#pragma unroll
      for (int m = 0; m < 6; ++m)
#pragma unroll
        for (int n = 0; n < 4; ++n)
          acc[m][n] = __builtin_amdgcn_mfma_f32_16x16x32_bf16(af[m], bf[n],
                                                              acc[m][n], 0, 0, 0);
    }
  }
#undef STAGE

  // ---- epilogue: store + BN partial stats ----
  const size_t ob = (((size_t)b * 384 + co0) << 10) + h0 * 32;
#pragma unroll
  for (int m = 0; m < 6; ++m) {
#pragma unroll
    for (int r = 0; r < 4; ++r) {
      const int co = m * 16 + d * 4 + r;     // within co tile
      float s = 0.f, q = 0.f;
#pragma unroll
      for (int n = 0; n < 4; ++n) {
        const float v = acc[m][n][r];
        const int p = wn * 64 + n * 16 + l15;  // 0..255 within 8-row strip
        out[ob + ((size_t)co << 10) + p] = v;
        s += v; q += v * v;
      }
#pragma unroll
      for (int off = 1; off < 16; off <<= 1) {
        s += __shfl_xor(s, off, 64);
        q += __shfl_xor(q, off, 64);
      }
      if (l15 == 0) {
        atomicAdd(&bn_sum[co0 + co], s);
        atomicAdd(&bn_sq[co0 + co], q);
      }
    }
  }
}

// ---------------- K6: BN finalize in place ----------------
__global__ __launch_bounds__(256) void k_bnfin(float* __restrict__ y,
                                               const float* __restrict__ bn_sum,
                                               const float* __restrict__ bn_sq,
                                               const float* __restrict__ gamma,
                                               const float* __restrict__ beta) {
  const size_t N4 = (size_t)32 * 384 * 1024 / 4;
  const float inv = 1.0f / 32768.0f;
  for (size_t i = (size_t)blockIdx.x * 256 + threadIdx.x; i < N4;
       i += (size_t)gridDim.x * 256) {
    const size_t e = i * 4;
    const int c = (int)((e >> 10) % 384);
    const float mu = bn_sum[c] * inv;
    const float var = fmaxf(bn_sq[c] * inv - mu * mu, 0.0f);
    const float rs = rsqrtf(var + 1e-5f) * gamma[c];
    const float bt = beta[c];
    float4 v = *reinterpret_cast<float4*>(y + e);
    v.x = (v.x - mu) * rs + bt;
    v.y = (v.y - mu) * rs + bt;
    v.z = (v.z - mu) * rs + bt;
    v.w = (v.w - mu) * rs + bt;
    *reinterpret_cast<float4*>(y + e) = v;
  }
}

extern "C" void kernel_launch(void* const* d_in, const int* in_sizes, int n_in,
                              void* d_out, int out_size, void* d_ws, size_t ws_size,
                              hipStream_t stream) {
  const float* x     = (const float*)d_in[0];
  const float* pmp   = (const float*)d_in[1];
  const float* psp   = (const float*)d_in[2];
  const float* pmn   = (const float*)d_in[3];
  const float* psn   = (const float*)d_in[4];
  const float* cw    = (const float*)d_in[5];
  const float* convw = (const float*)d_in[6];
  const float* gamma = (const float*)d_in[7];
  const float* beta  = (const float*)d_in[8];
  const int*   label = (const int*)d_in[9];
  float* out = (float*)d_out;
  char* ws = (char*)d_ws;

  // ws layout (~28 MB total)
  unsigned short* fea = (unsigned short*)(ws);                 // 25165824 B
  unsigned short* wb  = (unsigned short*)(ws + 25165824);      //  2654208 B
  float* sums  = (float*)(ws + 27820032);                      //    49152 B
  float* sumsq = (float*)(ws + 27869184);                      //    49152 B
  float* Ac    = (float*)(ws + 27918336);                      //    49152 B
  float* Bc    = (float*)(ws + 27967488);                      //    49152 B
  float* bn    = (float*)(ws + 28016640);                      //     3072 B
  float* zp    = (float*)(ws + 28019712);                      //     4096 B

  k_zero<<<dim3(1), dim3(256), 0, stream>>>(bn, zp);
  k_stats<<<dim3(12288), dim3(256), 0, stream>>>(x, sums, sumsq);
  k_coef<<<dim3(32), dim3(384), 0, stream>>>(pmp, psp, pmn, psn, cw, label,
                                             sums, sumsq, Ac, Bc);
  k_fea<<<dim3(128, 6), dim3(256), 0, stream>>>(x, Ac, Bc, fea);
  k_wcvt<<<dim3(1296), dim3(256), 0, stream>>>(convw, wb);
  k_conv<<<dim3(128, 4), dim3(256), 0, stream>>>(fea, wb, (const unsigned short*)zp,
                                                 out, bn, bn + 384);
  k_bnfin<<<dim3(2048), dim3(256), 0, stream>>>(out, bn, bn + 384, gamma, beta);
}

// Round 4
// 171.789 us; speedup vs baseline: 1.4239x; 1.4239x over previous
//
#include <hip/hip_runtime.h>
#include <stdint.h>

using f32x4  = __attribute__((ext_vector_type(4))) float;
using short8 = __attribute__((ext_vector_type(8))) short;

#define DEVI static __device__ __forceinline__

// float -> bf16 round-to-nearest-even
DEVI unsigned short f2bf(float f) {
  unsigned u = __float_as_uint(f);
  u += 0x7FFFu + ((u >> 16) & 1u);
  return (unsigned short)(u >> 16);
}

// async global->LDS, 16B per lane. LDS dest is wave-uniform base; HW writes
// base + lane*16. Global src is per-lane.
DEVI void gld16(const void* g, void* l) {
  __builtin_amdgcn_global_load_lds(
      reinterpret_cast<const __attribute__((address_space(1))) unsigned int*>(
          reinterpret_cast<uintptr_t>(g)),
      reinterpret_cast<__attribute__((address_space(3))) unsigned int*>(
          reinterpret_cast<uintptr_t>(l)),
      16, 0, 0);
}

// ---------------- K0: zero bn stats + global zero page ----------------
__global__ void k_zero(float* __restrict__ bn, float* __restrict__ zp) {
  const int t = threadIdx.x;
  for (int i = t; i < 768; i += 256) bn[i] = 0.0f;
  for (int i = t; i < 1024; i += 256) zp[i] = 0.0f;
}

// ---------------- K1: per-(b,c) sum / sumsq of x ----------------
__global__ __launch_bounds__(256) void k_stats(const float* __restrict__ x,
                                               float* __restrict__ sums,
                                               float* __restrict__ sumsq) {
  const int bc = blockIdx.x;  // 0..12287
  const float4 v =
      reinterpret_cast<const float4*>(x + (size_t)bc * 1024)[threadIdx.x];
  float s = v.x + v.y + v.z + v.w;
  float q = v.x * v.x + v.y * v.y + v.z * v.z + v.w * v.w;
#pragma unroll
  for (int off = 1; off < 64; off <<= 1) {
    s += __shfl_xor(s, off, 64);
    q += __shfl_xor(q, off, 64);
  }
  __shared__ float ls[4], lq[4];
  const int wv = threadIdx.x >> 6;
  if ((threadIdx.x & 63) == 0) { ls[wv] = s; lq[wv] = q; }
  __syncthreads();
  if (threadIdx.x == 0) {
    sums[bc]  = ls[0] + ls[1] + ls[2] + ls[3];
    sumsq[bc] = lq[0] + lq[1] + lq[2] + lq[3];
  }
}

// ---------------- K2: fold both CSA blocks into fea2 = A*x + B ----------------
__global__ __launch_bounds__(384) void k_coef(
    const float* __restrict__ pmp, const float* __restrict__ psp,
    const float* __restrict__ pmn, const float* __restrict__ psn,
    const float* __restrict__ cw, const int* __restrict__ label,
    const float* __restrict__ sums, const float* __restrict__ sumsq,
    float* __restrict__ Ac, float* __restrict__ Bc) {
  const int b = blockIdx.x;    // 0..31
  const int c = threadIdx.x;   // 0..383
  __shared__ float w0[64], w1[64];
  if (threadIdx.x < 64) w0[threadIdx.x] = cw[b * 64 + threadIdx.x];
  else if (threadIdx.x < 128) w1[threadIdx.x - 64] = cw[2048 + b * 64 + (threadIdx.x - 64)];
  __syncthreads();
  const bool sel = (label[b] == 0);
  const float* m1t = (sel ? pmp : pmn);           // layer 0 tables [K=64][C=384]
  const float* s1t = (sel ? psp : psn);
  const float* m2t = m1t + 64 * 384;              // layer 1
  const float* s2t = s1t + 64 * 384;
  float m1 = 0.f, s1 = 0.f, m2 = 0.f, s2 = 0.f;
  for (int k = 0; k < 64; ++k) {
    const float a0 = w0[k], a1 = w1[k];
    m1 += a0 * m1t[k * 384 + c];
    s1 += a0 * s1t[k * 384 + c];
    m2 += a1 * m2t[k * 384 + c];
    s2 += a1 * s2t[k * 384 + c];
  }
  const int bc = b * 384 + c;
  const float sum = sums[bc], sq = sumsq[bc];
  const float mean = sum * (1.0f / 1024.0f);
  float var = (sq - sum * mean) * (1.0f / 1023.0f);  // ddof=1
  var = fmaxf(var, 0.0f);
  const float sd1 = sqrtf(var + 1e-5f);
  const float a1c = 1.0f + s1 / sd1;
  const float b1c = m1 - mean * (s1 / sd1);
  const float mean1 = a1c * mean + b1c;      // exact mean of affine fea1
  const float var1  = a1c * a1c * var;       // exact ddof=1 var of affine fea1
  const float sd2 = sqrtf(var1 + 1e-5f);
  const float t2 = 1.0f + s2 / sd2;
  Ac[bc] = a1c * t2;
  Bc[bc] = b1c * t2 + m2 - mean1 * (s2 / sd2);
}

// ---------------- K3: fea2 NHWC bf16 = A*x + B (LDS transpose for writes) ----
// grid (128,6): block = 256 pixels x 64 channels
__global__ __launch_bounds__(256) void k_fea(const float* __restrict__ x,
                                             const float* __restrict__ Ac,
                                             const float* __restrict__ Bc,
                                             unsigned short* __restrict__ fea) {
  __shared__ unsigned short tb[256][68];   // +4 pad: bank-conflict-free
  const int t = threadIdx.x;
  const int g0 = blockIdx.x << 8;          // pixel base
  const int b = g0 >> 10;                  // uniform per block
  const int c0 = blockIdx.y * 64;
  const float* xb = x + (((size_t)b * 384) << 10) + (g0 & 1023) + t;
  const float* Ab = Ac + b * 384 + c0;
  const float* Bb = Bc + b * 384 + c0;
#pragma unroll 1
  for (int u8 = 0; u8 < 64; u8 += 8) {
    union { unsigned short us[8]; uint4 v; } pk;
#pragma unroll
    for (int u = 0; u < 8; ++u) {
      const int c = u8 + u;
      pk.us[u] = f2bf(Ab[c] * xb[(size_t)(c0 + c) << 10] + Bb[c]);
    }
    *reinterpret_cast<uint4*>(&tb[t][u8]) = pk.v;
  }
  __syncthreads();
  const int j = t & 7;
#pragma unroll
  for (int rep = 0; rep < 8; ++rep) {
    const int p = rep * 32 + (t >> 3);
    const uint4 v = *reinterpret_cast<const uint4*>(&tb[p][j * 8]);
    *reinterpret_cast<uint4*>(fea + (size_t)(g0 + p) * 384 + c0 + j * 8) = v;
  }
}

// ---------------- K4: conv_w (OIHW f32) -> wb[tap][co][ci] bf16 ----------------
__global__ __launch_bounds__(256) void k_wcvt(const float* __restrict__ w,
                                              unsigned short* __restrict__ wb) {
  const int e = (blockIdx.x * 256 + threadIdx.x) * 4;  // 9*384*384 = 1327104 exact
  const int t = e / (384 * 384);
  const int rem = e - t * (384 * 384);
  const int co = rem / 384;
  const int ci = rem - co * 384;
  union { unsigned short us[4]; uint2 v; } pk;
#pragma unroll
  for (int u = 0; u < 4; ++u)
    pk.us[u] = f2bf(w[(size_t)(co * 384 + ci + u) * 9 + t]);
  *reinterpret_cast<uint2*>(wb + e) = pk.v;
}

// ---------------- K5: implicit-GEMM conv + BN partial stats ----------------
// 256 thr = 4 waves. Block tile: 96co x 512pix (16 rows x 32 cols).
// Wave tile: 96co x 128pix = 6x8 frags of 16x16x32 bf16 MFMA (48 MFMA / 14
// ds_read_b128 per tap — 2x the read efficiency of the 96x64 tile).
// Grid 64x4 = 256 blocks = exactly 1 block/CU, single round.
// LDS (95 KiB, single buffer):
//   [0,55296)      W: 9 taps x 96co x 32ci, row=tap*96+co (64B), grp swizzled
//   [55296,92160)  IN: 18 rows x 32 cols x 32ci, row=pix (64B), grp swizzled
//   [92160,97280)  zero page (covers +dy*2048 walk)
// Swizzle: data grp g of row r stored at grp g ^ ((r>>1)&3); tap/m/dy-invariant.
__global__ __launch_bounds__(256, 1) void k_conv(
    const unsigned short* __restrict__ fea, const unsigned short* __restrict__ wb,
    const unsigned short* __restrict__ zpg, float* __restrict__ out,
    float* __restrict__ bn_sum, float* __restrict__ bn_sq) {
  __shared__ __align__(16) unsigned char lds[97280];
  const int tid = threadIdx.x;
  const int lane = tid & 63, wv = tid >> 6;
  const int pt = blockIdx.x;      // 0..63
  const int ct = blockIdx.y;      // 0..3
  const int b = pt >> 1, h0 = (pt & 1) * 16;
  const int co0 = ct * 96;
  const int wn = wv;              // pixel quarter (128 pix each)

  // zero the LDS zero-page
  for (int i = tid; i < 1280; i += 256)
    reinterpret_cast<float*>(lds + 92160)[i] = 0.0f;

  // ---- hoisted LDS read addresses ----
  const int l15 = lane & 15, d = lane >> 4;
  const int aoff = l15 * 64 + ((d ^ ((l15 >> 1) & 3)) << 4);
  int baddr[8][3];
#pragma unroll
  for (int n = 0; n < 8; ++n) {
    const int p_out = wn * 128 + n * 16 + l15;
    const int r_out = p_out >> 5, c_out = p_out & 31;
#pragma unroll
    for (int dx = 0; dx < 3; ++dx) {
      const int c = c_out + dx - 1;
      if ((unsigned)c < 32u) {
        const int pix = r_out * 32 + c;
        baddr[n][dx] = 55296 + pix * 64 + ((d ^ ((pix >> 1) & 3)) << 4);
      } else {
        baddr[n][dx] = 92160 + lane * 16;   // zero page (+dy*2048 stays zero)
      }
    }
  }

  // ---- hoisted staging source pointers (advance +64B per ci-chunk) ----
  const unsigned short* wp[14];
#pragma unroll
  for (int j = 0; j < 14; ++j) {
    const int s = wv + 4 * j;
    const int r = s * 16 + (lane >> 2);      // tap*96+co, < 864 when valid
    const int tap = (r * 683) >> 16;         // r/96 exact for r<864
    const int co = r - tap * 96;
    const int dd = (lane & 3) ^ ((co >> 1) & 3);
    wp[j] = wb + ((size_t)(tap * 384 + co0 + co) * 384 + dd * 8);
  }
  const unsigned short* ip[9];
  int istep[9];
#pragma unroll
  for (int j = 0; j < 9; ++j) {
    const int s = wv + 4 * j;                // 0..35
    const int pix = s * 16 + (lane >> 2);    // 0..575
    const int prow = pix >> 5, pcol = pix & 31;
    const int h = h0 - 1 + prow;
    const int dd = (lane & 3) ^ ((pix >> 1) & 3);
    if (h >= 0 && h < 32) {
      ip[j] = fea + ((size_t)((b * 32 + h) * 32 + pcol) * 384 + dd * 8);
      istep[j] = 32;
    } else {
      ip[j] = zpg + lane * 8;
      istep[j] = 0;
    }
  }

  f32x4 acc[6][8] = {};

  for (int cc = 0; cc < 12; ++cc) {
    __syncthreads();
#pragma unroll
    for (int j = 0; j < 14; ++j) {
      if (j < 13 || wv < 2) {                // 54 W slabs: 14,14,13,13
        gld16(wp[j], lds + (wv + 4 * j) * 1024);
        wp[j] += 32;
      }
    }
#pragma unroll
    for (int j = 0; j < 9; ++j) {            // 36 IN slabs: 9 per wave
      gld16(ip[j], lds + 55296 + (wv + 4 * j) * 1024);
      ip[j] += istep[j];
    }
    __syncthreads();
#pragma unroll
    for (int tap = 0; tap < 9; ++tap) {
      const int dy = tap / 3, dx = tap % 3;
      short8 af[6], bf[8];
#pragma unroll
      for (int m = 0; m < 6; ++m)
        af[m] = *reinterpret_cast<const short8*>(lds + aoff + tap * 6144 + m * 1024);
#pragma unroll
      for (int n = 0; n < 8; ++n)
        bf[n] = *reinterpret_cast<const short8*>(lds + baddr[n][dx] + dy * 2048);
#pragma unroll
      for (int m = 0; m < 6; ++m)
#pragma unroll
        for (int n = 0; n < 8; ++n)
          acc[m][n] = __builtin_amdgcn_mfma_f32_16x16x32_bf16(af[m], bf[n],
                                                              acc[m][n], 0, 0, 0);
    }
  }

  // ---- epilogue: store + BN partial stats ----
  const size_t ob = (((size_t)b * 384 + co0) << 10) + h0 * 32;
#pragma unroll
  for (int m = 0; m < 6; ++m) {
#pragma unroll
    for (int r = 0; r < 4; ++r) {
      const int co = m * 16 + d * 4 + r;     // within co tile
      float s = 0.f, q = 0.f;
#pragma unroll
      for (int n = 0; n < 8; ++n) {
        const float v = acc[m][n][r];
        const int p = wn * 128 + n * 16 + l15;  // 0..511 within 16-row strip
        out[ob + ((size_t)co << 10) + p] = v;
        s += v; q += v * v;
      }
#pragma unroll
      for (int off = 1; off < 16; off <<= 1) {
        s += __shfl_xor(s, off, 64);
        q += __shfl_xor(q, off, 64);
      }
      if (l15 == 0) {
        atomicAdd(&bn_sum[co0 + co], s);
        atomicAdd(&bn_sq[co0 + co], q);
      }
    }
  }
}

// ---------------- K6: BN finalize in place ----------------
__global__ __launch_bounds__(256) void k_bnfin(float* __restrict__ y,
                                               const float* __restrict__ bn_sum,
                                               const float* __restrict__ bn_sq,
                                               const float* __restrict__ gamma,
                                               const float* __restrict__ beta) {
  const size_t N4 = (size_t)32 * 384 * 1024 / 4;
  const float inv = 1.0f / 32768.0f;
  for (size_t i = (size_t)blockIdx.x * 256 + threadIdx.x; i < N4;
       i += (size_t)gridDim.x * 256) {
    const size_t e = i * 4;
    const int c = (int)((e >> 10) % 384);
    const float mu = bn_sum[c] * inv;
    const float var = fmaxf(bn_sq[c] * inv - mu * mu, 0.0f);
    const float rs = rsqrtf(var + 1e-5f) * gamma[c];
    const float bt = beta[c];
    float4 v = *reinterpret_cast<float4*>(y + e);
    v.x = (v.x - mu) * rs + bt;
    v.y = (v.y - mu) * rs + bt;
    v.z = (v.z - mu) * rs + bt;
    v.w = (v.w - mu) * rs + bt;
    *reinterpret_cast<float4*>(y + e) = v;
  }
}

extern "C" void kernel_launch(void* const* d_in, const int* in_sizes, int n_in,
                              void* d_out, int out_size, void* d_ws, size_t ws_size,
                              hipStream_t stream) {
  const float* x     = (const float*)d_in[0];
  const float* pmp   = (const float*)d_in[1];
  const float* psp   = (const float*)d_in[2];
  const float* pmn   = (const float*)d_in[3];
  const float* psn   = (const float*)d_in[4];
  const float* cw    = (const float*)d_in[5];
  const float* convw = (const float*)d_in[6];
  const float* gamma = (const float*)d_in[7];
  const float* beta  = (const float*)d_in[8];
  const int*   label = (const int*)d_in[9];
  float* out = (float*)d_out;
  char* ws = (char*)d_ws;

  // ws layout (~28 MB total)
  unsigned short* fea = (unsigned short*)(ws);                 // 25165824 B
  unsigned short* wb  = (unsigned short*)(ws + 25165824);      //  2654208 B
  float* sums  = (float*)(ws + 27820032);                      //    49152 B
  float* sumsq = (float*)(ws + 27869184);                      //    49152 B
  float* Ac    = (float*)(ws + 27918336);                      //    49152 B
  float* Bc    = (float*)(ws + 27967488);                      //    49152 B
  float* bn    = (float*)(ws + 28016640);                      //     3072 B
  float* zp    = (float*)(ws + 28019712);                      //     4096 B

  k_zero<<<dim3(1), dim3(256), 0, stream>>>(bn, zp);
  k_stats<<<dim3(12288), dim3(256), 0, stream>>>(x, sums, sumsq);
  k_coef<<<dim3(32), dim3(384), 0, stream>>>(pmp, psp, pmn, psn, cw, label,
                                             sums, sumsq, Ac, Bc);
  k_fea<<<dim3(128, 6), dim3(256), 0, stream>>>(x, Ac, Bc, fea);
  k_wcvt<<<dim3(1296), dim3(256), 0, stream>>>(convw, wb);
  k_conv<<<dim3(64, 4), dim3(256), 0, stream>>>(fea, wb, (const unsigned short*)zp,
                                                out, bn, bn + 384);
  k_bnfin<<<dim3(2048), dim3(256), 0, stream>>>(out, bn, bn + 384, gamma, beta);
}